// Round 9
// baseline (744.722 us; speedup 1.0000x reference)
//
#include <hip/hip_runtime.h>
#include <hip/hip_bf16.h>

// DGCNN-style KNN classifier. B=8, N=2048, K=10.
// g_flag=1 -> bf16 inputs, 0 -> fp32 (runtime probe). Output same dtype.
// Scratch in static __device__ globals; every byte read is written earlier in
// the same launch (graph-replay safe; norms re-initialized each launch).
//
// R26: swapped-operand KNN. R25 showed the per-tile cost is the LDS
// transpose machinery (sd write + barrier + scan ~430 VALU/wave/tile), not
// addressing. mfma(A,B) -> D[row from A][col from B]; swapping to
// mfma(m_frag, q_frag) makes col=lane&15 the QUERY -> each lane holds 16
// register-resident distances for its own query per 64-m tile. No sd LDS,
// no main-loop barriers, no pass bitmask. Each wave owns 16 queries; per
// query 4 quad-lanes keep top-10 over disjoint m-subsets (16 lists/query
// globally, same as R25). Threshold = min over quad-lanes' K[9] via 2
// __shfl_xor (exact: min of subset-10th-bests >= partition 10th-best).
// Candidates statically unrolled (16 positions) - no runtime-indexed reg
// arrays. One-time LDS merge (4 quad-lists -> 10) at kernel end; g_pk
// format and epilogue unchanged.

#define NEG 0.2f
#define FMAX 3.402823466e+38f
#define KINIT 0x7F7FFFFFFFFFFFFFull  // (FLT_MAX bits << 32) | 0xFFFFFFFF

typedef __hip_bfloat16 bf16;
typedef __attribute__((ext_vector_type(8))) short s8v;    // 8 bf16
typedef __attribute__((ext_vector_type(4))) float f32x4;  // MFMA acc
typedef unsigned long long u64;

#define BB 8
#define NN 2048
#define BNTOT (BB * NN)
#define NPART 4

#define OFF_NORMS ((size_t)0)
#define OFF_PART (OFF_NORMS + BNTOT)
#define OFF_POOLED (OFF_PART + 8 * 1024 * 32)
#define OFF_H1 (OFF_POOLED + 8 * 1024)
#define OFF_H2 (OFF_H1 + 8 * 512)
#define WSF_TOTAL (OFF_H2 + 8 * 256)

// frag-tiled W1..W4 halves: base[l] + z*half[l] + i
#define WB1 0
#define WB2 4096
#define WB3 12288
#define WB4 28672
#define WTOT 94208

__device__ float g_ws_f[WSF_TOTAL];
__device__ float g_G[(size_t)8 * BNTOT * 64];     // [chunk(<=4)][z(2)][BN][64]
__device__ u64 g_pk[(size_t)BNTOT * NPART * 10];  // partial top-10 packed keys
__device__ int g_flag;                            // 1 = bf16 inputs, 0 = fp32
__device__ unsigned short g_hi[(size_t)BNTOT * 512];    // knn/gmat split (frag-tiled)
__device__ unsigned short g_lo[(size_t)BNTOT * 512];
__device__ unsigned short g_xhi5[(size_t)BNTOT * 512];  // W5-layout activations
__device__ unsigned short g_xlo5[(size_t)BNTOT * 512];
__device__ unsigned short g_whi[1024 * 512];            // split W5 weights
__device__ unsigned short g_wlo[1024 * 512];
__device__ unsigned short g_wfh[WTOT];                  // split W1..W4 (frag-tiled)
__device__ unsigned short g_wfl[WTOT];

__device__ __forceinline__ float ldany(const void* p, size_t i, int isb) {
  if (isb) return __bfloat162float(((const bf16*)p)[i]);
  return ((const float*)p)[i];
}

// ---------------- dtype probe ----------------
__global__ void probe_kernel(const void* pts) {
  const unsigned* w = (const unsigned*)pts;
  int cnt = 0;
  for (int i = 0; i < 256; ++i) {
    unsigned e2 = (w[i] >> 7) & 0xFF;
    cnt += (e2 >= 110 && e2 <= 135);
  }
  g_flag = (cnt > 128) ? 1 : 0;
}

// ---------------- norms (layer-1 input only) ----------------
__global__ void norms_kernel(const void* xraw, int lda, int C, int BN) {
  const int isb = g_flag;
  float* norms = g_ws_f + OFF_NORMS;
  int row = blockIdx.x * (blockDim.x >> 6) + (threadIdx.x >> 6);
  int lane = threadIdx.x & 63;
  if (row >= BN) return;
  float s = 0.f;
  for (int c = lane; c < C; c += 64) {
    float v = ldany(xraw, (size_t)row * lda + c, isb);
    s += v * v;
  }
#pragma unroll
  for (int off = 32; off > 0; off >>= 1) s += __shfl_down(s, off, 64);
  if (lane == 0) norms[row] = s;
}

__global__ void zero_norms() {
  int i = blockIdx.x * blockDim.x + threadIdx.x;
  if (i < BNTOT) g_ws_f[OFF_NORMS + i] = 0.f;
}

// ------- split-bf16 into MFMA-fragment-tile layout (points + W5 weights) -------
__global__ void split_kernel(const void* xraw, int lda, int C,
                             int csh2, int dst, int total) {
  int i = blockIdx.x * blockDim.x + threadIdx.x;
  if (i >= total) return;
  const int isb = g_flag;
  int t = i >> 9, win = i & 511;
  int quad = win >> 7, l16 = (win >> 3) & 15, j = win & 7;
  int ktiles_m1 = (1 << csh2) - 1;
  int rg = t >> csh2, kt = t & ktiles_m1;
  int r = rg * 16 + l16;
  int c = kt * 32 + quad * 8 + j;
  float v = (c < C) ? ldany(xraw, (size_t)r * lda + c, isb) : 0.f;
  bf16 h = __float2bfloat16(v);
  float hf = __bfloat162float(h);
  bf16 l = __float2bfloat16(v - hf);
  unsigned short* H = dst ? g_whi : g_hi;
  unsigned short* L = dst ? g_wlo : g_lo;
  H[i] = *(unsigned short*)&h;
  L[i] = *(unsigned short*)&l;
}

// ------- split W-halves (W1..W4) into frag-tiled g_wfh/g_wfl; z = blockIdx.y -------
__global__ void split_w(const void* W, int C, int ktsh, int wbase, int whalf,
                        int total) {
  int i = blockIdx.x * blockDim.x + threadIdx.x;
  if (i >= total) return;
  int z = blockIdx.y;
  const int isb = g_flag;
  int t = i >> 9, win = i & 511;
  int quad = win >> 7, l16 = (win >> 3) & 15, j = win & 7;
  int rg = t >> ktsh, kt = t & ((1 << ktsh) - 1);
  int orow = rg * 16 + l16;
  int c = kt * 32 + quad * 8 + j;
  float v = (c < C) ? ldany(W, (size_t)orow * (2 * C) + (size_t)z * C + c, isb) : 0.f;
  bf16 h = __float2bfloat16(v);
  float hf = __bfloat162float(h);
  bf16 l = __float2bfloat16(v - hf);
  g_wfh[wbase + z * whalf + i] = *(unsigned short*)&h;
  g_wfl[wbase + z * whalf + i] = *(unsigned short*)&l;
}

__device__ __forceinline__ void insert10(u64* K, float d, int m) {
  u64 key = ((u64)__float_as_uint(fmaxf(d, 0.f)) << 32) | (unsigned)m;
  if (key < K[9]) {
    bool prev = true;
#pragma unroll
    for (int s2 = 9; s2 >= 1; --s2) {
      bool sh = key < K[s2 - 1];
      K[s2] = sh ? K[s2 - 1] : (prev ? key : K[s2]);
      prev = sh;
    }
    if (prev) K[0] = key;
  }
}

// ------- fused KNN (partitioned, swapped operands): distances land in the
// owning lane's registers. No main-loop LDS/barriers. Wave owns 16 queries
// (col = lane&15); quad = lane>>4 owns m-subset {m0 + s*16 + quad*4 + r}.
template <int CPAD>
__global__ __launch_bounds__(256) void knn_fused(int N) {
  constexpr int KT = CPAD >> 5;
  __shared__ __align__(16) u64 mbuf[4][16 * 4 * 10];  // 20480 B, end-merge only
  const int tid = threadIdx.x;
  const int wave = tid >> 6, lane = tid & 63;
  const int quad = lane >> 4, l16 = lane & 15;
  const int b = blockIdx.y;
  const int q0 = blockIdx.x * 64;
  const int part = blockIdx.z;
  const int PN = N / NPART;
  const int rowb = b * N;
  const float* norms = g_ws_f + OFF_NORMS;

  // q-fragment for this wave's 16 queries (used as the B operand)
  const int qrg = ((rowb + q0) >> 4) + wave;
  s8v qh[KT], ql[KT];
#pragma unroll
  for (int kt = 0; kt < KT; ++kt) {
    const int qbase = (qrg * KT + kt) * 512 + lane * 8;
    qh[kt] = *(const s8v*)(g_hi + qbase);
    ql[kt] = *(const s8v*)(g_lo + qbase);
  }

  const int selfq = q0 + wave * 16 + l16;  // this lane's query
  const float qn = norms[rowb + selfq];
  u64 K[10];
#pragma unroll
  for (int i = 0; i < 10; ++i) K[i] = KINIT;

  for (int m0 = part * PN; m0 < (part + 1) * PN; m0 += 64) {
    // m-norms for this quad's 4 consecutive m per s-subtile (16B-aligned)
    f32x4 nmv[4];
#pragma unroll
    for (int s = 0; s < 4; ++s)
      nmv[s] = *(const f32x4*)(norms + rowb + m0 + s * 16 + quad * 4);
    f32x4 acc[4];
#pragma unroll
    for (int s = 0; s < 4; ++s) acc[s] = (f32x4){0.f, 0.f, 0.f, 0.f};
    const int mrg0 = (rowb + m0) >> 4;
#pragma unroll
    for (int kt = 0; kt < KT; ++kt) {
#pragma unroll
      for (int s = 0; s < 4; ++s) {
        const int moff = ((mrg0 + s) * KT + kt) * 512 + lane * 8;
        s8v mh = *(const s8v*)(g_hi + moff);
        s8v ml = *(const s8v*)(g_lo + moff);
        // swapped: D[row=m][col=q]; col=lane&15 is this lane's query
        acc[s] = __builtin_amdgcn_mfma_f32_16x16x32_bf16(mh, qh[kt], acc[s], 0, 0, 0);
        acc[s] = __builtin_amdgcn_mfma_f32_16x16x32_bf16(ml, qh[kt], acc[s], 0, 0, 0);
        acc[s] = __builtin_amdgcn_mfma_f32_16x16x32_bf16(mh, ql[kt], acc[s], 0, 0, 0);
      }
    }
    // threshold: min of the 4 quad-lanes' K[9] for this query (register-only)
    float myk9 = __uint_as_float((unsigned)(K[9] >> 32));
    float t2 = fminf(myk9, __shfl_xor(myk9, 16, 64));
    float T = fminf(t2, __shfl_xor(t2, 32, 64));
    const float Tq = T - qn;  // d' = nm - 2dot; d' <= Tq <=> qn + d' <= T
    // self-exclusion mask (bit s*4+r), nonzero only if selfq in this quad's slots
    unsigned selfmask = 0;
    {
      unsigned ds_ = (unsigned)(selfq - m0);
      if (ds_ < 64u && (((ds_ >> 2) & 3u) == (unsigned)quad))
        selfmask = 1u << (((ds_ >> 4) << 2) | (ds_ & 3u));
    }
    // statically unrolled candidate processing (16 register-resident dists)
#pragma unroll
    for (int s = 0; s < 4; ++s) {
#pragma unroll
      for (int r = 0; r < 4; ++r) {
        float dp = fmaf(-2.f, acc[s][r], nmv[s][r]);
        if (!((selfmask >> (s * 4 + r)) & 1u) && dp <= Tq)
          insert10(K, dp + qn, m0 + s * 16 + quad * 4 + r);
      }
    }
  }
  // end-merge: each query's 4 quad-lists -> top-10 -> g_pk (one-time)
  u64* wl = mbuf[wave];
#pragma unroll
  for (int i = 0; i < 10; ++i) wl[(l16 * 4 + quad) * 10 + i] = K[i];
  __syncthreads();
  if (l16 == lane) {  // lanes 0..15 of each wave (quad==0)
    int q = l16;
    int p0 = 0, p1 = 0, p2 = 0, p3 = 0;
    size_t ob = ((size_t)(rowb + q0 + wave * 16 + q) * NPART + part) * 10;
    for (int cnt = 0; cnt < 10; ++cnt) {
      u64 k0 = wl[(q * 4 + 0) * 10 + p0];
      u64 k1 = wl[(q * 4 + 1) * 10 + p1];
      u64 k2 = wl[(q * 4 + 2) * 10 + p2];
      u64 k3 = wl[(q * 4 + 3) * 10 + p3];
      u64 bk = k0; int bp = 0;
      if (k1 < bk) { bk = k1; bp = 1; }
      if (k2 < bk) { bk = k2; bp = 2; }
      if (k3 < bk) { bk = k3; bp = 3; }
      if (bp == 0) ++p0; else if (bp == 1) ++p1; else if (bp == 2) ++p2; else ++p3;
      g_pk[ob + cnt] = bk;
    }
  }
}

// --- G[chunk][z] = X @ W_half^T via MFMA; A from g_hi/g_lo, B from g_wfh/g_wfl ---
template <int CPAD>
__global__ __launch_bounds__(256) void gmat_mfma(int wbase, int whalf, int BN) {
  constexpr int KT = CPAD >> 5;
  const int tid = threadIdx.x;
  const int wave = tid >> 6, lane = tid & 63;
  const int quad = lane >> 4, l16 = lane & 15;
  const int r0 = blockIdx.x * 64;
  const int chunk = blockIdx.y;
  const int z = blockIdx.z;
  const int wz = wbase + z * whalf;
  const int wrg0 = chunk * 4;
  f32x4 acc[4];
#pragma unroll
  for (int s = 0; s < 4; ++s) acc[s] = (f32x4){0.f, 0.f, 0.f, 0.f};
  const int arg = (r0 >> 4) + wave;
#pragma unroll
  for (int kt = 0; kt < KT; ++kt) {
    const int abase = (arg * KT + kt) * 512 + lane * 8;
    s8v ah = *(const s8v*)(g_hi + abase);
    s8v al = *(const s8v*)(g_lo + abase);
#pragma unroll
    for (int s = 0; s < 4; ++s) {
      const int woff = wz + ((wrg0 + s) * KT + kt) * 512 + lane * 8;
      s8v bh = *(const s8v*)(g_wfh + woff);
      s8v bl = *(const s8v*)(g_wfl + woff);
      acc[s] = __builtin_amdgcn_mfma_f32_16x16x32_bf16(ah, bh, acc[s], 0, 0, 0);
      acc[s] = __builtin_amdgcn_mfma_f32_16x16x32_bf16(ah, bl, acc[s], 0, 0, 0);
      acc[s] = __builtin_amdgcn_mfma_f32_16x16x32_bf16(al, bh, acc[s], 0, 0, 0);
    }
  }
  float* Gz = g_G + (size_t)(chunk * 2 + z) * BN * 64;
#pragma unroll
  for (int s = 0; s < 4; ++s)
#pragma unroll
    for (int r = 0; r < 4; ++r)
      Gz[(r0 + wave * 16 + quad * 4 + r) * 64 + s * 16 + l16] = acc[s][r];
}

// ------- edge-conv epilogue: inline NPART-merge (rank-select) + gather+max
//         + fused splits + norms. One wave per row.
__global__ void edge_epi64(const void* s, const void* t, int colbase,
                           int knn_csh2, int norms_mode, int BN, int N) {
  __shared__ u64 kbuf[4][40];
  __shared__ int oidx[4][10];
  const int isb = g_flag;
  int tid = threadIdx.x;
  int p = tid >> 6, o = tid & 63;  // p = wave = row-in-block
  int row = blockIdx.x * 4 + p;
  int chunk = blockIdx.y;
  const float* G1 = g_G + (size_t)(chunk * 2 + 0) * BN * 64;
  const float* G2 = g_G + (size_t)(chunk * 2 + 1) * BN * 64;
  int b = row / N;
  if (o < 40) kbuf[p][o] = g_pk[(size_t)row * 40 + o];
  if (o < 40) {
    u64 myk = kbuf[p][o];
    int rank = 0;
#pragma unroll 8
    for (int j = 0; j < 40; ++j) rank += (kbuf[p][j] < myk);
    if (rank < 10) oidx[p][rank] = (int)(myk & 0xFFFFFFFFu);
  }
  float g1n = G1[row * 64 + o];
  float base = G2[row * 64 + o] - g1n;
  int co = chunk * 64 + o;
  float sv = ldany(s, co, isb), tv = ldany(t, co, isb);
  float mx = -FMAX;
  const int bn64 = b * N * 64;
#pragma unroll
  for (int k = 0; k < 10; ++k) {
    int m = oidx[p][k];
    m = (m < 0) ? 0 : ((m >= N) ? N - 1 : m);
    float h = sv * (G1[bn64 + m * 64 + o] + base) + tv;
    h = (h >= 0.f) ? h : NEG * h;
    mx = fmaxf(mx, h);
  }
  bf16 h16 = __float2bfloat16(mx);
  float hf = __bfloat162float(h16);
  bf16 l16v = __float2bfloat16(mx - hf);
  unsigned short hu = *(unsigned short*)&h16;
  unsigned short lu = *(unsigned short*)&l16v;
  if (knn_csh2 >= 0) {
    int KTL = 1 << knn_csh2;
    int ki = ((row >> 4) * KTL + (co >> 5)) * 512 +
             ((co >> 3) & 3) * 128 + (row & 15) * 8 + (co & 7);
    g_hi[ki] = hu; g_lo[ki] = lu;
  }
  {
    int gc = colbase + co;
    int wi = ((row >> 4) * 16 + (gc >> 5)) * 512 +
             ((gc >> 3) & 3) * 128 + (row & 15) * 8 + (gc & 7);
    g_xhi5[wi] = hu; g_xlo5[wi] = lu;
  }
  if (norms_mode) {
    float ns = mx * mx;
#pragma unroll
    for (int off = 32; off > 0; off >>= 1) ns += __shfl_down(ns, off, 64);
    if (o == 0) {
      if (norms_mode == 1) g_ws_f[OFF_NORMS + row] = ns;
      else atomicAdd(&g_ws_f[OFF_NORMS + row], ns);
    }
  }
}

// ------- W5 MFMA + max over n; wave tile 64n x 64o (s5>0: affine after max) ----
__global__ __launch_bounds__(256) void w5max_mfma(const void* s5, const void* t5, int N) {
  const int tid = threadIdx.x;
  const int wave = tid >> 6, lane = tid & 63;
  const int quad = lane >> 4, l16 = lane & 15;
  const int b = blockIdx.z;
  const int o0 = blockIdx.y * 64, n0 = blockIdx.x * 256;
  f32x4 acc[4][4];
#pragma unroll
  for (int a = 0; a < 4; ++a)
#pragma unroll
    for (int s = 0; s < 4; ++s) acc[a][s] = (f32x4){0.f, 0.f, 0.f, 0.f};

  const int arg0 = ((b * N + n0) >> 4) + wave * 4;
  const int wrg0 = o0 >> 4;
  for (int kt = 0; kt < 16; ++kt) {
    s8v ah[4], al[4];
#pragma unroll
    for (int a = 0; a < 4; ++a) {
      const int abase = ((arg0 + a) * 16 + kt) * 512 + lane * 8;
      ah[a] = *(const s8v*)(g_xhi5 + abase);
      al[a] = *(const s8v*)(g_xlo5 + abase);
    }
#pragma unroll
    for (int s = 0; s < 4; ++s) {
      const int bbase = ((wrg0 + s) * 16 + kt) * 512 + lane * 8;
      s8v bh = *(const s8v*)(g_whi + bbase);
      s8v bl = *(const s8v*)(g_wlo + bbase);
#pragma unroll
      for (int a = 0; a < 4; ++a) {
        acc[a][s] = __builtin_amdgcn_mfma_f32_16x16x32_bf16(ah[a], bh, acc[a][s], 0, 0, 0);
        acc[a][s] = __builtin_amdgcn_mfma_f32_16x16x32_bf16(ah[a], bl, acc[a][s], 0, 0, 0);
        acc[a][s] = __builtin_amdgcn_mfma_f32_16x16x32_bf16(al[a], bh, acc[a][s], 0, 0, 0);
      }
    }
  }
  __shared__ float red[4][64];
  const int isb = g_flag;
#pragma unroll
  for (int s = 0; s < 4; ++s) {
    float m4 = -FMAX;
#pragma unroll
    for (int a = 0; a < 4; ++a)
#pragma unroll
      for (int r = 0; r < 4; ++r) m4 = fmaxf(m4, acc[a][s][r]);
#pragma unroll
    for (int off = 16; off < 64; off <<= 1) m4 = fmaxf(m4, __shfl_down(m4, off, 64));
    if (quad == 0) red[wave][s * 16 + l16] = m4;
  }
  __syncthreads();
  if (tid < 64) {
    float m = fmaxf(fmaxf(red[0][tid], red[1][tid]), fmaxf(red[2][tid], red[3][tid]));
    int o = o0 + tid;
    float sv = ldany(s5, o, isb), tv = ldany(t5, o, isb);
    float h = sv * m + tv;
    h = (h >= 0.f) ? h : NEG * h;
    g_ws_f[OFF_PART + ((size_t)b * 1024 + o) * 8 + blockIdx.x] = h;
  }
}

__global__ void poolred_kernel() {
  const float* part = g_ws_f + OFF_PART;
  float* pooled = g_ws_f + OFF_POOLED;
  int i = blockIdx.x * blockDim.x + threadIdx.x;
  if (i >= 8 * 1024) return;
  const float* p = part + (size_t)i * 8;
  float m = -FMAX;
#pragma unroll
  for (int j = 0; j < 8; ++j) m = fmaxf(m, p[j]);
  pooled[i] = m;
}

// ---------------- FC: one wave per output ----------------
__global__ void fc_kernel(size_t inoff, const void* W, const void* bias,
                          const void* s, const void* t, size_t outoff, int has_out,
                          void* OUTB, int Bb, int IC, int OC, int act) {
  const int isb = g_flag;
  const float* IN = g_ws_f + inoff;
  int gw = (blockIdx.x * blockDim.x + threadIdx.x) >> 6;
  int lane = threadIdx.x & 63;
  if (gw >= Bb * OC) return;
  int b = gw / OC, o = gw % OC;
  const float* in = IN + (size_t)b * IC;
  float acc = 0.f;
  for (int c = lane; c < IC; c += 64) acc += in[c] * ldany(W, (size_t)o * IC + c, isb);
#pragma unroll
  for (int off = 32; off > 0; off >>= 1) acc += __shfl_down(acc, off, 64);
  if (lane == 0) {
    float h = acc;
    if (bias) h += ldany(bias, o, isb);
    if (s) h = h * ldany(s, o, isb) + ldany(t, o, isb);
    if (act) h = (h >= 0.f) ? h : NEG * h;
    if (has_out) g_ws_f[outoff + (size_t)b * OC + o] = h;
    if (OUTB) {
      if (isb) ((bf16*)OUTB)[(size_t)b * OC + o] = __float2bfloat16(h);
      else ((float*)OUTB)[(size_t)b * OC + o] = h;
    }
  }
}

extern "C" void kernel_launch(void* const* d_in, const int* in_sizes, int n_in,
                              void* d_out, int out_size, void* d_ws, size_t ws_size,
                              hipStream_t stream) {
  const int B = 8, N = 2048, BN = B * N;
  const void* points = d_in[0];
  const void *W1 = d_in[1], *s1 = d_in[2], *t1 = d_in[3];
  const void *W2 = d_in[4], *s2 = d_in[5], *t2 = d_in[6];
  const void *W3 = d_in[7], *s3 = d_in[8], *t3 = d_in[9];
  const void *W4 = d_in[10], *s4 = d_in[11], *t4 = d_in[12];
  const void *W5 = d_in[13], *s5 = d_in[14], *t5 = d_in[15];
  const void *Wf1 = d_in[16], *sf1 = d_in[17], *tf1 = d_in[18];
  const void *Wf2 = d_in[19], *bf2 = d_in[20], *sf2 = d_in[21], *tf2 = d_in[22];
  const void *Wf3 = d_in[23], *bf3 = d_in[24];

  probe_kernel<<<1, 1, 0, stream>>>(points);
  split_kernel<<<(1024 * 512) / 256, 256, 0, stream>>>(W5, 512, 512, 4, 1, 1024 * 512);
  split_w<<<dim3(2048 / 256, 2), 256, 0, stream>>>(W1, 3, 0, WB1, 2048, 2048);
  split_w<<<dim3(4096 / 256, 2), 256, 0, stream>>>(W2, 64, 1, WB2, 4096, 4096);
  split_w<<<dim3(8192 / 256, 2), 256, 0, stream>>>(W3, 64, 1, WB3, 8192, 8192);
  split_w<<<dim3(32768 / 256, 2), 256, 0, stream>>>(W4, 128, 2, WB4, 32768, 32768);

  // ---- layer 1: points (C=3, CPAD=32) -> cols 0:64
  norms_kernel<<<BN / 4, 256, 0, stream>>>(points, 3, 3, BN);
  split_kernel<<<(BN * 32) / 256, 256, 0, stream>>>(points, 3, 3, 0, 0, BN * 32);
  knn_fused<32><<<dim3(N / 64, B, NPART), 256, 0, stream>>>(N);
  gmat_mfma<32><<<dim3(BN / 64, 1, 2), 256, 0, stream>>>(WB1, 2048, BN);
  edge_epi64<<<dim3(BN / 4, 1), 256, 0, stream>>>(s1, t1, 0, 1, 1, BN, N);
  // ---- layer 2: (C=64, CPAD=64) -> cols 64:128
  knn_fused<64><<<dim3(N / 64, B, NPART), 256, 0, stream>>>(N);
  gmat_mfma<64><<<dim3(BN / 64, 1, 2), 256, 0, stream>>>(WB2, 4096, BN);
  edge_epi64<<<dim3(BN / 4, 1), 256, 0, stream>>>(s2, t2, 64, 1, 1, BN, N);
  // ---- layer 3: (C=64) -> cols 128:256, 2 chunks; next layer CPAD=128
  knn_fused<64><<<dim3(N / 64, B, NPART), 256, 0, stream>>>(N);
  gmat_mfma<64><<<dim3(BN / 64, 2, 2), 256, 0, stream>>>(WB3, 8192, BN);
  zero_norms<<<BN / 256, 256, 0, stream>>>();
  edge_epi64<<<dim3(BN / 4, 2), 256, 0, stream>>>(s3, t3, 128, 2, 2, BN, N);
  // ---- layer 4: (C=128) -> cols 256:512, 4 chunks; no next knn
  knn_fused<128><<<dim3(N / 64, B, NPART), 256, 0, stream>>>(N);
  gmat_mfma<128><<<dim3(BN / 64, 4, 2), 256, 0, stream>>>(WB4, 32768, BN);
  edge_epi64<<<dim3(BN / 4, 4), 256, 0, stream>>>(s4, t4, 256, -1, 0, BN, N);
  // ---- W5 + global max pool
  w5max_mfma<<<dim3(8, 16, 8), 256, 0, stream>>>(s5, t5, N);
  poolred_kernel<<<32, 256, 0, stream>>>();
  // ---- FC head
  fc_kernel<<<(8 * 512 * 64) / 256, 256, 0, stream>>>(OFF_POOLED, Wf1, nullptr, sf1, tf1, OFF_H1, 1, nullptr, 8, 1024, 512, 1);
  fc_kernel<<<(8 * 256 * 64) / 256, 256, 0, stream>>>(OFF_H1, Wf2, bf2, sf2, tf2, OFF_H2, 1, nullptr, 8, 512, 256, 1);
  fc_kernel<<<6, 256, 0, stream>>>(OFF_H2, Wf3, bf3, nullptr, nullptr, 0, 0, d_out, 8, 256, 3, 0);
}

// Round 10
// 470.131 us; speedup vs baseline: 1.5841x; 1.5841x over previous
//
#include <hip/hip_runtime.h>
#include <hip/hip_bf16.h>

// DGCNN-style KNN classifier. B=8, N=2048, K=10.
// g_flag=1 -> bf16 inputs, 0 -> fp32 (runtime probe). Output same dtype.
// Scratch in static __device__ globals; every byte read is written earlier in
// the same launch (graph-replay safe; norms re-initialized each launch).
//
// R27 = R25 (best verified: NPART=4, dbuf sd, 1 barrier/tile, block-local LDS
// threshold, 32-bit addressing) + u32 packed keys in the knn top-10 lists.
// R26's register-resident swapped layout regressed (static 16-slot unroll
// executes ~16 u64 insert bodies/wave/tile under divergence). Here the insert
// stays in R25's while(ctz) form but the key is 32-bit: upper 23 bits =
// fp32 distance bits with low 9 masked, low 9 bits = m - part*PN (<512).
// Insert step: v_cmp_lt_u32 + 2 cndmask_b32 (~3 inst vs u64's ~6); K list
// 20->10 VGPRs. Exact w.r.t. masked-key ordering: for any partition-top-10
// key c, at most 9 keys < c exist, so every list's K9 >= c at all times ->
// bits(d_c) < masked(K9)+0x200 <= published tb of every list -> c passes the
// min-threshold prefilter and the strict insert guard (keys are distinct:
// distinct m -> distinct low bits). Masking = 2^-15 relative distance
// quantization, same order as the existing bf16-split arithmetic error.

#define NEG 0.2f
#define FMAX 3.402823466e+38f
#define KINIT32 0xFFFFFFFFu

typedef __hip_bfloat16 bf16;
typedef __attribute__((ext_vector_type(8))) short s8v;    // 8 bf16
typedef __attribute__((ext_vector_type(4))) float f32x4;  // MFMA acc
typedef unsigned long long u64;

#define BB 8
#define NN 2048
#define BNTOT (BB * NN)
#define NPART 4

#define OFF_NORMS ((size_t)0)
#define OFF_PART (OFF_NORMS + BNTOT)
#define OFF_POOLED (OFF_PART + 8 * 1024 * 32)
#define OFF_H1 (OFF_POOLED + 8 * 1024)
#define OFF_H2 (OFF_H1 + 8 * 512)
#define WSF_TOTAL (OFF_H2 + 8 * 256)

// frag-tiled W1..W4 halves: base[l] + z*half[l] + i
#define WB1 0
#define WB2 4096
#define WB3 12288
#define WB4 28672
#define WTOT 94208

__device__ float g_ws_f[WSF_TOTAL];
__device__ float g_G[(size_t)8 * BNTOT * 64];     // [chunk(<=4)][z(2)][BN][64]
__device__ u64 g_pk[(size_t)BNTOT * NPART * 10];  // partial top-10 packed keys
__device__ int g_flag;                            // 1 = bf16 inputs, 0 = fp32
__device__ unsigned short g_hi[(size_t)BNTOT * 512];    // knn/gmat split (frag-tiled)
__device__ unsigned short g_lo[(size_t)BNTOT * 512];
__device__ unsigned short g_xhi5[(size_t)BNTOT * 512];  // W5-layout activations
__device__ unsigned short g_xlo5[(size_t)BNTOT * 512];
__device__ unsigned short g_whi[1024 * 512];            // split W5 weights
__device__ unsigned short g_wlo[1024 * 512];
__device__ unsigned short g_wfh[WTOT];                  // split W1..W4 (frag-tiled)
__device__ unsigned short g_wfl[WTOT];

__device__ __forceinline__ float ldany(const void* p, size_t i, int isb) {
  if (isb) return __bfloat162float(((const bf16*)p)[i]);
  return ((const float*)p)[i];
}

// ---------------- dtype probe ----------------
__global__ void probe_kernel(const void* pts) {
  const unsigned* w = (const unsigned*)pts;
  int cnt = 0;
  for (int i = 0; i < 256; ++i) {
    unsigned e2 = (w[i] >> 7) & 0xFF;
    cnt += (e2 >= 110 && e2 <= 135);
  }
  g_flag = (cnt > 128) ? 1 : 0;
}

// ---------------- norms (layer-1 input only) ----------------
__global__ void norms_kernel(const void* xraw, int lda, int C, int BN) {
  const int isb = g_flag;
  float* norms = g_ws_f + OFF_NORMS;
  int row = blockIdx.x * (blockDim.x >> 6) + (threadIdx.x >> 6);
  int lane = threadIdx.x & 63;
  if (row >= BN) return;
  float s = 0.f;
  for (int c = lane; c < C; c += 64) {
    float v = ldany(xraw, (size_t)row * lda + c, isb);
    s += v * v;
  }
#pragma unroll
  for (int off = 32; off > 0; off >>= 1) s += __shfl_down(s, off, 64);
  if (lane == 0) norms[row] = s;
}

__global__ void zero_norms() {
  int i = blockIdx.x * blockDim.x + threadIdx.x;
  if (i < BNTOT) g_ws_f[OFF_NORMS + i] = 0.f;
}

// ------- split-bf16 into MFMA-fragment-tile layout (points + W5 weights) -------
__global__ void split_kernel(const void* xraw, int lda, int C,
                             int csh2, int dst, int total) {
  int i = blockIdx.x * blockDim.x + threadIdx.x;
  if (i >= total) return;
  const int isb = g_flag;
  int t = i >> 9, win = i & 511;
  int quad = win >> 7, l16 = (win >> 3) & 15, j = win & 7;
  int ktiles_m1 = (1 << csh2) - 1;
  int rg = t >> csh2, kt = t & ktiles_m1;
  int r = rg * 16 + l16;
  int c = kt * 32 + quad * 8 + j;
  float v = (c < C) ? ldany(xraw, (size_t)r * lda + c, isb) : 0.f;
  bf16 h = __float2bfloat16(v);
  float hf = __bfloat162float(h);
  bf16 l = __float2bfloat16(v - hf);
  unsigned short* H = dst ? g_whi : g_hi;
  unsigned short* L = dst ? g_wlo : g_lo;
  H[i] = *(unsigned short*)&h;
  L[i] = *(unsigned short*)&l;
}

// ------- split W-halves (W1..W4) into frag-tiled g_wfh/g_wfl; z = blockIdx.y -------
__global__ void split_w(const void* W, int C, int ktsh, int wbase, int whalf,
                        int total) {
  int i = blockIdx.x * blockDim.x + threadIdx.x;
  if (i >= total) return;
  int z = blockIdx.y;
  const int isb = g_flag;
  int t = i >> 9, win = i & 511;
  int quad = win >> 7, l16 = (win >> 3) & 15, j = win & 7;
  int rg = t >> ktsh, kt = t & ((1 << ktsh) - 1);
  int orow = rg * 16 + l16;
  int c = kt * 32 + quad * 8 + j;
  float v = (c < C) ? ldany(W, (size_t)orow * (2 * C) + (size_t)z * C + c, isb) : 0.f;
  bf16 h = __float2bfloat16(v);
  float hf = __bfloat162float(h);
  bf16 l = __float2bfloat16(v - hf);
  g_wfh[wbase + z * whalf + i] = *(unsigned short*)&h;
  g_wfl[wbase + z * whalf + i] = *(unsigned short*)&l;
}

__device__ __forceinline__ void insert10u(unsigned* K, unsigned key) {
  if (key < K[9]) {
    bool prev = true;
#pragma unroll
    for (int s2 = 9; s2 >= 1; --s2) {
      bool sh = key < K[s2 - 1];
      K[s2] = sh ? K[s2 - 1] : (prev ? key : K[s2]);
      prev = sh;
    }
    if (prev) K[0] = key;
  }
}

// ------- fused KNN (partitioned): MFMA distances + per-partition top-10 -------
// Double-buffered sd (one barrier/tile). Block-local LDS threshold; u32 keys.
template <int CPAD>
__global__ __launch_bounds__(256) void knn_fused(int N) {
  constexpr int KT = CPAD >> 5;
  __shared__ __align__(16) float sdbuf[2][64 * 68];  // 34816 B
  __shared__ float th_sh[4][64];                     // +1 KB
  const int tid = threadIdx.x;
  const int wave = tid >> 6, lane = tid & 63;
  const int quad = lane >> 4, l16 = lane & 15;
  const int b = blockIdx.y;
  const int q0 = blockIdx.x * 64;
  const int part = blockIdx.z;
  const int PN = N / NPART;
  const int partbase = part * PN;
  const int rowb = b * N;                            // fits int
  const float* norms = g_ws_f + OFF_NORMS;

  const int arg = ((rowb + q0) >> 4) + wave;
  s8v ah[KT], al[KT];
#pragma unroll
  for (int kt = 0; kt < KT; ++kt) {
    const int abase = (arg * KT + kt) * 512 + lane * 8;
    ah[kt] = *(const s8v*)(g_hi + abase);
    al[kt] = *(const s8v*)(g_lo + abase);
  }

  const int selfn = q0 + lane;  // this thread maintains query q0+lane
  const float qn = norms[rowb + selfn];
  unsigned K[10];
#pragma unroll
  for (int i = 0; i < 10; ++i) K[i] = KINIT32;
  th_sh[wave][lane] = FMAX;  // first read is after tile-0's barrier

  int pb = 0;
  for (int m0 = partbase; m0 < partbase + PN; m0 += 64, pb ^= 1) {
    float nmv[4];
#pragma unroll
    for (int s = 0; s < 4; ++s) nmv[s] = norms[rowb + m0 + s * 16 + l16];
    f32x4 acc[4];
#pragma unroll
    for (int s = 0; s < 4; ++s) acc[s] = (f32x4){0.f, 0.f, 0.f, 0.f};
    const int brg0 = (rowb + m0) >> 4;
    const int btile = brg0 * (KT * 512) + lane * 8;
#pragma unroll
    for (int kt = 0; kt < KT; ++kt) {
#pragma unroll
      for (int s = 0; s < 4; ++s) {
        const int boff = btile + (s * KT + kt) * 512;
        s8v bh = *(const s8v*)(g_hi + boff);
        s8v bl = *(const s8v*)(g_lo + boff);
        acc[s] = __builtin_amdgcn_mfma_f32_16x16x32_bf16(ah[kt], bh, acc[s], 0, 0, 0);
        acc[s] = __builtin_amdgcn_mfma_f32_16x16x32_bf16(ah[kt], bl, acc[s], 0, 0, 0);
        acc[s] = __builtin_amdgcn_mfma_f32_16x16x32_bf16(al[kt], bh, acc[s], 0, 0, 0);
      }
    }
    float* sd = sdbuf[pb];
#pragma unroll
    for (int s = 0; s < 4; ++s) {
      int ml = s * 16 + l16;
#pragma unroll
      for (int r = 0; r < 4; ++r)
        sd[(wave * 16 + quad * 4 + r) * 68 + ml] = nmv[s] - 2.f * acc[s][r];
    }
    __syncthreads();  // single barrier per tile; also publishes th_sh
    // block-local bound: min over the 4 wave-lists for this query + own tb
    float T = fminf(fminf(th_sh[0][lane], th_sh[1][lane]),
                    fminf(th_sh[2][lane], th_sh[3][lane]));
    {
      unsigned tb = K[9] & 0xFFFFFE00u;
      tb = (tb >= 0x7F7FFE00u) ? 0x7F800000u : tb + 0x200u;
      T = fminf(T, __uint_as_float(tb));
    }
    const float Tq = T - qn;  // stored d' = nm - 2dot; d'<=Tq <=> qn+d'<=T
    const int mbase = m0 + wave * 16;
    const int mrelbase = mbase - partbase;  // [0, 512)
    const float* srow = sd + lane * 68 + wave * 16;
    unsigned pass = 0;
#pragma unroll
    for (int jj = 0; jj < 16; jj += 4) {
      float4 d4 = *(const float4*)(srow + jj);
      pass |= (unsigned)(d4.x <= Tq) << jj;
      pass |= (unsigned)(d4.y <= Tq) << (jj + 1);
      pass |= (unsigned)(d4.z <= Tq) << (jj + 2);
      pass |= (unsigned)(d4.w <= Tq) << (jj + 3);
    }
    if ((unsigned)(selfn - mbase) < 16u) pass &= ~(1u << (selfn - mbase));
    while (pass) {
      int jj = __builtin_ctz(pass);
      pass &= pass - 1;
      float d = fmaxf(srow[jj] + qn, 0.f);
      unsigned key = (__float_as_uint(d) & 0xFFFFFE00u) | (unsigned)(mrelbase + jj);
      insert10u(K, key);
    }
    // publish own bound (+1 quantum so equal-masked keys aren't prefiltered)
    {
      unsigned tb = K[9] & 0xFFFFFE00u;
      tb = (tb >= 0x7F7FFE00u) ? 0x7F800000u : tb + 0x200u;
      th_sh[wave][lane] = __uint_as_float(tb);
    }
  }
  __syncthreads();  // sd dead; reuse sdbuf for merge lists
  unsigned* mlist = (unsigned*)sdbuf;
#pragma unroll
  for (int i = 0; i < 10; ++i) mlist[(lane * 4 + wave) * 10 + i] = K[i];
  __syncthreads();
  if (tid < 64) {
    int q = tid;
    int p0 = 0, p1 = 0, p2 = 0, p3 = 0;
    size_t ob = ((size_t)(rowb + q0 + q) * NPART + part) * 10;
    for (int cnt = 0; cnt < 10; ++cnt) {
      unsigned k0 = mlist[(q * 4 + 0) * 10 + p0];
      unsigned k1 = mlist[(q * 4 + 1) * 10 + p1];
      unsigned k2 = mlist[(q * 4 + 2) * 10 + p2];
      unsigned k3 = mlist[(q * 4 + 3) * 10 + p3];
      unsigned bk = k0; int bp = 0;
      if (k1 < bk) { bk = k1; bp = 1; }
      if (k2 < bk) { bk = k2; bp = 2; }
      if (k3 < bk) { bk = k3; bp = 3; }
      if (bp == 0) ++p0; else if (bp == 1) ++p1; else if (bp == 2) ++p2; else ++p3;
      // expand u32 key -> u64 g_pk format (masked dist bits, global m)
      g_pk[ob + cnt] = ((u64)(bk & 0xFFFFFE00u) << 32) |
                       (unsigned)(partbase + (int)(bk & 0x1FFu));
    }
  }
}

// --- G[chunk][z] = X @ W_half^T via MFMA; A from g_hi/g_lo, B from g_wfh/g_wfl ---
template <int CPAD>
__global__ __launch_bounds__(256) void gmat_mfma(int wbase, int whalf, int BN) {
  constexpr int KT = CPAD >> 5;
  const int tid = threadIdx.x;
  const int wave = tid >> 6, lane = tid & 63;
  const int quad = lane >> 4, l16 = lane & 15;
  const int r0 = blockIdx.x * 64;
  const int chunk = blockIdx.y;
  const int z = blockIdx.z;
  const int wz = wbase + z * whalf;
  const int wrg0 = chunk * 4;
  f32x4 acc[4];
#pragma unroll
  for (int s = 0; s < 4; ++s) acc[s] = (f32x4){0.f, 0.f, 0.f, 0.f};
  const int arg = (r0 >> 4) + wave;
#pragma unroll
  for (int kt = 0; kt < KT; ++kt) {
    const int abase = (arg * KT + kt) * 512 + lane * 8;
    s8v ah = *(const s8v*)(g_hi + abase);
    s8v al = *(const s8v*)(g_lo + abase);
#pragma unroll
    for (int s = 0; s < 4; ++s) {
      const int woff = wz + ((wrg0 + s) * KT + kt) * 512 + lane * 8;
      s8v bh = *(const s8v*)(g_wfh + woff);
      s8v bl = *(const s8v*)(g_wfl + woff);
      acc[s] = __builtin_amdgcn_mfma_f32_16x16x32_bf16(ah, bh, acc[s], 0, 0, 0);
      acc[s] = __builtin_amdgcn_mfma_f32_16x16x32_bf16(ah, bl, acc[s], 0, 0, 0);
      acc[s] = __builtin_amdgcn_mfma_f32_16x16x32_bf16(al, bh, acc[s], 0, 0, 0);
    }
  }
  float* Gz = g_G + (size_t)(chunk * 2 + z) * BN * 64;
#pragma unroll
  for (int s = 0; s < 4; ++s)
#pragma unroll
    for (int r = 0; r < 4; ++r)
      Gz[(r0 + wave * 16 + quad * 4 + r) * 64 + s * 16 + l16] = acc[s][r];
}

// ------- edge-conv epilogue: inline NPART-merge (rank-select) + gather+max
//         + fused splits + norms. One wave per row.
__global__ void edge_epi64(const void* s, const void* t, int colbase,
                           int knn_csh2, int norms_mode, int BN, int N) {
  __shared__ u64 kbuf[4][40];
  __shared__ int oidx[4][10];
  const int isb = g_flag;
  int tid = threadIdx.x;
  int p = tid >> 6, o = tid & 63;  // p = wave = row-in-block
  int row = blockIdx.x * 4 + p;
  int chunk = blockIdx.y;
  const float* G1 = g_G + (size_t)(chunk * 2 + 0) * BN * 64;
  const float* G2 = g_G + (size_t)(chunk * 2 + 1) * BN * 64;
  int b = row / N;
  if (o < 40) kbuf[p][o] = g_pk[(size_t)row * 40 + o];
  if (o < 40) {
    u64 myk = kbuf[p][o];
    int rank = 0;
#pragma unroll 8
    for (int j = 0; j < 40; ++j) rank += (kbuf[p][j] < myk);
    if (rank < 10) oidx[p][rank] = (int)(myk & 0xFFFFFFFFu);
  }
  float g1n = G1[row * 64 + o];
  float base = G2[row * 64 + o] - g1n;
  int co = chunk * 64 + o;
  float sv = ldany(s, co, isb), tv = ldany(t, co, isb);
  float mx = -FMAX;
  const int bn64 = b * N * 64;
#pragma unroll
  for (int k = 0; k < 10; ++k) {
    int m = oidx[p][k];
    m = (m < 0) ? 0 : ((m >= N) ? N - 1 : m);
    float h = sv * (G1[bn64 + m * 64 + o] + base) + tv;
    h = (h >= 0.f) ? h : NEG * h;
    mx = fmaxf(mx, h);
  }
  bf16 h16 = __float2bfloat16(mx);
  float hf = __bfloat162float(h16);
  bf16 l16v = __float2bfloat16(mx - hf);
  unsigned short hu = *(unsigned short*)&h16;
  unsigned short lu = *(unsigned short*)&l16v;
  if (knn_csh2 >= 0) {
    int KTL = 1 << knn_csh2;
    int ki = ((row >> 4) * KTL + (co >> 5)) * 512 +
             ((co >> 3) & 3) * 128 + (row & 15) * 8 + (co & 7);
    g_hi[ki] = hu; g_lo[ki] = lu;
  }
  {
    int gc = colbase + co;
    int wi = ((row >> 4) * 16 + (gc >> 5)) * 512 +
             ((gc >> 3) & 3) * 128 + (row & 15) * 8 + (gc & 7);
    g_xhi5[wi] = hu; g_xlo5[wi] = lu;
  }
  if (norms_mode) {
    float ns = mx * mx;
#pragma unroll
    for (int off = 32; off > 0; off >>= 1) ns += __shfl_down(ns, off, 64);
    if (o == 0) {
      if (norms_mode == 1) g_ws_f[OFF_NORMS + row] = ns;
      else atomicAdd(&g_ws_f[OFF_NORMS + row], ns);
    }
  }
}

// ------- W5 MFMA + max over n; wave tile 64n x 64o (s5>0: affine after max) ----
__global__ __launch_bounds__(256) void w5max_mfma(const void* s5, const void* t5, int N) {
  const int tid = threadIdx.x;
  const int wave = tid >> 6, lane = tid & 63;
  const int quad = lane >> 4, l16 = lane & 15;
  const int b = blockIdx.z;
  const int o0 = blockIdx.y * 64, n0 = blockIdx.x * 256;
  f32x4 acc[4][4];
#pragma unroll
  for (int a = 0; a < 4; ++a)
#pragma unroll
    for (int s = 0; s < 4; ++s) acc[a][s] = (f32x4){0.f, 0.f, 0.f, 0.f};

  const int arg0 = ((b * N + n0) >> 4) + wave * 4;
  const int wrg0 = o0 >> 4;
  for (int kt = 0; kt < 16; ++kt) {
    s8v ah[4], al[4];
#pragma unroll
    for (int a = 0; a < 4; ++a) {
      const int abase = ((arg0 + a) * 16 + kt) * 512 + lane * 8;
      ah[a] = *(const s8v*)(g_xhi5 + abase);
      al[a] = *(const s8v*)(g_xlo5 + abase);
    }
#pragma unroll
    for (int s = 0; s < 4; ++s) {
      const int bbase = ((wrg0 + s) * 16 + kt) * 512 + lane * 8;
      s8v bh = *(const s8v*)(g_whi + bbase);
      s8v bl = *(const s8v*)(g_wlo + bbase);
#pragma unroll
      for (int a = 0; a < 4; ++a) {
        acc[a][s] = __builtin_amdgcn_mfma_f32_16x16x32_bf16(ah[a], bh, acc[a][s], 0, 0, 0);
        acc[a][s] = __builtin_amdgcn_mfma_f32_16x16x32_bf16(ah[a], bl, acc[a][s], 0, 0, 0);
        acc[a][s] = __builtin_amdgcn_mfma_f32_16x16x32_bf16(al[a], bh, acc[a][s], 0, 0, 0);
      }
    }
  }
  __shared__ float red[4][64];
  const int isb = g_flag;
#pragma unroll
  for (int s = 0; s < 4; ++s) {
    float m4 = -FMAX;
#pragma unroll
    for (int a = 0; a < 4; ++a)
#pragma unroll
      for (int r = 0; r < 4; ++r) m4 = fmaxf(m4, acc[a][s][r]);
#pragma unroll
    for (int off = 16; off < 64; off <<= 1) m4 = fmaxf(m4, __shfl_down(m4, off, 64));
    if (quad == 0) red[wave][s * 16 + l16] = m4;
  }
  __syncthreads();
  if (tid < 64) {
    float m = fmaxf(fmaxf(red[0][tid], red[1][tid]), fmaxf(red[2][tid], red[3][tid]));
    int o = o0 + tid;
    float sv = ldany(s5, o, isb), tv = ldany(t5, o, isb);
    float h = sv * m + tv;
    h = (h >= 0.f) ? h : NEG * h;
    g_ws_f[OFF_PART + ((size_t)b * 1024 + o) * 8 + blockIdx.x] = h;
  }
}

__global__ void poolred_kernel() {
  const float* part = g_ws_f + OFF_PART;
  float* pooled = g_ws_f + OFF_POOLED;
  int i = blockIdx.x * blockDim.x + threadIdx.x;
  if (i >= 8 * 1024) return;
  const float* p = part + (size_t)i * 8;
  float m = -FMAX;
#pragma unroll
  for (int j = 0; j < 8; ++j) m = fmaxf(m, p[j]);
  pooled[i] = m;
}

// ---------------- FC: one wave per output ----------------
__global__ void fc_kernel(size_t inoff, const void* W, const void* bias,
                          const void* s, const void* t, size_t outoff, int has_out,
                          void* OUTB, int Bb, int IC, int OC, int act) {
  const int isb = g_flag;
  const float* IN = g_ws_f + inoff;
  int gw = (blockIdx.x * blockDim.x + threadIdx.x) >> 6;
  int lane = threadIdx.x & 63;
  if (gw >= Bb * OC) return;
  int b = gw / OC, o = gw % OC;
  const float* in = IN + (size_t)b * IC;
  float acc = 0.f;
  for (int c = lane; c < IC; c += 64) acc += in[c] * ldany(W, (size_t)o * IC + c, isb);
#pragma unroll
  for (int off = 32; off > 0; off >>= 1) acc += __shfl_down(acc, off, 64);
  if (lane == 0) {
    float h = acc;
    if (bias) h += ldany(bias, o, isb);
    if (s) h = h * ldany(s, o, isb) + ldany(t, o, isb);
    if (act) h = (h >= 0.f) ? h : NEG * h;
    if (has_out) g_ws_f[outoff + (size_t)b * OC + o] = h;
    if (OUTB) {
      if (isb) ((bf16*)OUTB)[(size_t)b * OC + o] = __float2bfloat16(h);
      else ((float*)OUTB)[(size_t)b * OC + o] = h;
    }
  }
}

extern "C" void kernel_launch(void* const* d_in, const int* in_sizes, int n_in,
                              void* d_out, int out_size, void* d_ws, size_t ws_size,
                              hipStream_t stream) {
  const int B = 8, N = 2048, BN = B * N;
  const void* points = d_in[0];
  const void *W1 = d_in[1], *s1 = d_in[2], *t1 = d_in[3];
  const void *W2 = d_in[4], *s2 = d_in[5], *t2 = d_in[6];
  const void *W3 = d_in[7], *s3 = d_in[8], *t3 = d_in[9];
  const void *W4 = d_in[10], *s4 = d_in[11], *t4 = d_in[12];
  const void *W5 = d_in[13], *s5 = d_in[14], *t5 = d_in[15];
  const void *Wf1 = d_in[16], *sf1 = d_in[17], *tf1 = d_in[18];
  const void *Wf2 = d_in[19], *bf2 = d_in[20], *sf2 = d_in[21], *tf2 = d_in[22];
  const void *Wf3 = d_in[23], *bf3 = d_in[24];

  probe_kernel<<<1, 1, 0, stream>>>(points);
  split_kernel<<<(1024 * 512) / 256, 256, 0, stream>>>(W5, 512, 512, 4, 1, 1024 * 512);
  split_w<<<dim3(2048 / 256, 2), 256, 0, stream>>>(W1, 3, 0, WB1, 2048, 2048);
  split_w<<<dim3(4096 / 256, 2), 256, 0, stream>>>(W2, 64, 1, WB2, 4096, 4096);
  split_w<<<dim3(8192 / 256, 2), 256, 0, stream>>>(W3, 64, 1, WB3, 8192, 8192);
  split_w<<<dim3(32768 / 256, 2), 256, 0, stream>>>(W4, 128, 2, WB4, 32768, 32768);

  // ---- layer 1: points (C=3, CPAD=32) -> cols 0:64
  norms_kernel<<<BN / 4, 256, 0, stream>>>(points, 3, 3, BN);
  split_kernel<<<(BN * 32) / 256, 256, 0, stream>>>(points, 3, 3, 0, 0, BN * 32);
  knn_fused<32><<<dim3(N / 64, B, NPART), 256, 0, stream>>>(N);
  gmat_mfma<32><<<dim3(BN / 64, 1, 2), 256, 0, stream>>>(WB1, 2048, BN);
  edge_epi64<<<dim3(BN / 4, 1), 256, 0, stream>>>(s1, t1, 0, 1, 1, BN, N);
  // ---- layer 2: (C=64, CPAD=64) -> cols 64:128
  knn_fused<64><<<dim3(N / 64, B, NPART), 256, 0, stream>>>(N);
  gmat_mfma<64><<<dim3(BN / 64, 1, 2), 256, 0, stream>>>(WB2, 4096, BN);
  edge_epi64<<<dim3(BN / 4, 1), 256, 0, stream>>>(s2, t2, 64, 1, 1, BN, N);
  // ---- layer 3: (C=64) -> cols 128:256, 2 chunks; next layer CPAD=128
  knn_fused<64><<<dim3(N / 64, B, NPART), 256, 0, stream>>>(N);
  gmat_mfma<64><<<dim3(BN / 64, 2, 2), 256, 0, stream>>>(WB3, 8192, BN);
  zero_norms<<<BN / 256, 256, 0, stream>>>();
  edge_epi64<<<dim3(BN / 4, 2), 256, 0, stream>>>(s3, t3, 128, 2, 2, BN, N);
  // ---- layer 4: (C=128) -> cols 256:512, 4 chunks; no next knn
  knn_fused<128><<<dim3(N / 64, B, NPART), 256, 0, stream>>>(N);
  gmat_mfma<128><<<dim3(BN / 64, 4, 2), 256, 0, stream>>>(WB4, 32768, BN);
  edge_epi64<<<dim3(BN / 4, 4), 256, 0, stream>>>(s4, t4, 256, -1, 0, BN, N);
  // ---- W5 + global max pool
  w5max_mfma<<<dim3(8, 16, 8), 256, 0, stream>>>(s5, t5, N);
  poolred_kernel<<<32, 256, 0, stream>>>();
  // ---- FC head
  fc_kernel<<<(8 * 512 * 64) / 256, 256, 0, stream>>>(OFF_POOLED, Wf1, nullptr, sf1, tf1, OFF_H1, 1, nullptr, 8, 1024, 512, 1);
  fc_kernel<<<(8 * 256 * 64) / 256, 256, 0, stream>>>(OFF_H1, Wf2, bf2, sf2, tf2, OFF_H2, 1, nullptr, 8, 512, 256, 1);
  fc_kernel<<<6, 256, 0, stream>>>(OFF_H2, Wf3, bf3, nullptr, nullptr, 0, 0, d_out, 8, 256, 3, 0);
}